// Round 8
// baseline (321.532 us; speedup 1.0000x reference)
//
#include <hip/hip_runtime.h>
#include <hip/hip_bf16.h>

#define NB   64
#define SL   1024
#define EMB  128
#define NSK  1000
#define TI   64    // i-tile rows

using short8  = __attribute__((ext_vector_type(8))) short;
using floatx4 = __attribute__((ext_vector_type(4))) float;

// log5(x) = log2(x) * INV_LOG2_5
#define INV_LOG2_5 0.43067655807339306f

// Balanced j-tile permutation: slot s (=bid>>6) -> jt nibble.
// P = [15,13,11,9, 0,2,4,6, 14,12,10,8, 1,3,5,7]: every {s,s+4,s+8,s+12}
// quadruple sums to 30 => with the measured block->CU mapping (XCD round-robin
// bid%8, stride-32 within XCD; r7 data: pred 40-tile CU-max matched 55us) every
// CU gets exactly 34 tiles of work.
#define JT_PATTERN 0x75318ACE64209BDFULL

__device__ inline unsigned cvt2(float x, float y) {
    float2 f; f.x = x; f.y = y;
    __hip_bfloat162 h = __float22bfloat162_rn(f);
    unsigned u; __builtin_memcpy(&u, &h, sizeof(u));
    return u;
}

// exact fp32 path for duplicate-timestamp pairs (dt==0, i<j):
// contribution = alpha_dot * exp(beta' * 14.306765580733931)   [= -log(1e-10)/log(5)]
__device__ float fixup_pair(const float* __restrict__ air,
                            const float* __restrict__ bir,
                            const float* __restrict__ asr,
                            const float* __restrict__ bsr) {
    float da = 0.f, db = 0.f;
#pragma unroll 8
    for (int k = 0; k < EMB; k += 4) {
        float4 a  = *(const float4*)(air + k);
        float4 s  = *(const float4*)(asr + k);
        float4 bq = *(const float4*)(bir + k);
        float4 tt = *(const float4*)(bsr + k);
        da += a.x * s.x + a.y * s.y + a.z * s.z + a.w * s.w;
        db += bq.x * tt.x + bq.y * tt.y + bq.z * tt.z + bq.w * tt.w;
    }
    float beta = fminf(fmaxf(db + 1.f, 0.f), 10.f);
    return da * __expf(beta * 14.30676558073393f);
}

// ---- half-tile (32 rows x 2 mats) staging, fp32 source ----
// thread role: row = tid>>3 (0..31), mat = (tid>>2)&1, sq = tid&3 (32-elem quarter)
struct StageF { float4 f0, f1, f2, f3, f4, f5, f6, f7; };

__device__ __forceinline__ StageF stagef_load(const int* __restrict__ binp,
                                              const float* __restrict__ mat,
                                              int half, int row, int sq)
{
    const int arow = half * 32 + row;
    const long intr = binp[arow] + (long)binp[2 * SL + arow] * NSK;
    const float* p = mat + intr * (long)EMB + sq * 32;
    StageF s;
    s.f0 = *(const float4*)(p);      s.f1 = *(const float4*)(p + 4);
    s.f2 = *(const float4*)(p + 8);  s.f3 = *(const float4*)(p + 12);
    s.f4 = *(const float4*)(p + 16); s.f5 = *(const float4*)(p + 20);
    s.f6 = *(const float4*)(p + 24); s.f7 = *(const float4*)(p + 28);
    return s;
}

// proven swizzle (0 conflicts measured r1): 16B chunk c of row r stored at
// byte ((((c>>1)^(r&7)) + ((c&1)<<3)) << 4) within the row's 256B.
// Conversion (identical rounding to the old cvt_tables) happens here, at the
// write site, so the raw fp32 prefetch keeps flying until this point.
__device__ __forceinline__ void stageh_write_cvt(char* buf, int row, long matoff,
                                                 int wslot, const StageF& f)
{
    const uint4 q0 = make_uint4(cvt2(f.f0.x, f.f0.y), cvt2(f.f0.z, f.f0.w),
                                cvt2(f.f1.x, f.f1.y), cvt2(f.f1.z, f.f1.w));
    const uint4 q1 = make_uint4(cvt2(f.f2.x, f.f2.y), cvt2(f.f2.z, f.f2.w),
                                cvt2(f.f3.x, f.f3.y), cvt2(f.f3.z, f.f3.w));
    const uint4 q2 = make_uint4(cvt2(f.f4.x, f.f4.y), cvt2(f.f4.z, f.f4.w),
                                cvt2(f.f5.x, f.f5.y), cvt2(f.f5.z, f.f5.w));
    const uint4 q3 = make_uint4(cvt2(f.f6.x, f.f6.y), cvt2(f.f6.z, f.f6.w),
                                cvt2(f.f7.x, f.f7.y), cvt2(f.f7.z, f.f7.w));
    char* p  = buf + matoff + row * 256 + wslot;
    char* px = buf + matoff + row * 256 + (wslot ^ 16);
    *(uint4*)(p)        = q0;  *(uint4*)(p + 128)  = q1;
    *(uint4*)(px)       = q2;  *(uint4*)(px + 128) = q3;
}

// ============================================================================
// hawkes_fused v10: r7 structure (fused finalize, ping-pong 32-row halves,
// 2-deep register prefetch, verified conflict-free swizzle) with
//   (1) balanced jt permutation -> every CU gets exactly 34 tiles
//   (2) fp32->bf16 conversion inlined at the LDS-write site (cvt_tables kernel
//       and the bf16 workspace table deleted; bit-identical rounding).
// ============================================================================
extern "C" __global__ __launch_bounds__(256, 4)
void hawkes_fused(const int*   __restrict__ inp,     // (B,4,L) int32
                  const float* __restrict__ pbase,
                  const float* __restrict__ sbase,
                  const float* __restrict__ ai, const float* __restrict__ as,
                  const float* __restrict__ bi, const float* __restrict__ bs,
                  float*       __restrict__ out)
{
    __shared__ uint4 ldsq[2048];                    // 32 KB: 2 bufs x (2 mats x 32 rows x 256B)
    char* ldsc = (char*)ldsq;

    const int bid  = blockIdx.x;                    // grid = 16 * NB = 1024
    const int b    = bid & (NB - 1);
    const int jt   = (int)((JT_PATTERN >> ((bid >> 6) << 2)) & 15);
    const int tid  = threadIdx.x;
    const int w    = tid >> 6;                      // wave -> 16-j strip
    const int l    = tid & 63;
    const int quad = l >> 4;
    const int col  = l & 15;

    const int* __restrict__ binp = inp + b * 4 * SL;

    const int jlane = jt * TI + w * 16 + col;
    const int sk_j  = binp[jlane];
    const int tj    = binp[3 * SL + jlane];

    // ---- B fragments (skill rows of this lane's j) from fp32, cvt in regs ----
    short8 bfa[4], bfb[4];
    {
        const float* asr = as + (long)sk_j * EMB + quad * 8;
        const float* bsr = bs + (long)sk_j * EMB + quad * 8;
        union UF { uint4 u; short8 s8; };
#pragma unroll
        for (int ks = 0; ks < 4; ++ks) {
            float4 a0 = *(const float4*)(asr + ks * 32);
            float4 a1 = *(const float4*)(asr + ks * 32 + 4);
            float4 b0 = *(const float4*)(bsr + ks * 32);
            float4 b1 = *(const float4*)(bsr + ks * 32 + 4);
            UF ua, ub;
            ua.u = make_uint4(cvt2(a0.x, a0.y), cvt2(a0.z, a0.w),
                              cvt2(a1.x, a1.y), cvt2(a1.z, a1.w));
            ub.u = make_uint4(cvt2(b0.x, b0.y), cvt2(b0.z, b0.w),
                              cvt2(b1.x, b1.y), cvt2(b1.z, b1.w));
            bfa[ks] = ua.s8;
            bfb[ks] = ub.s8;
        }
    }

    // ---- staging role ----
    const int   srow   = tid >> 3;                  // 0..31
    const int   mymat  = (tid >> 2) & 1;
    const float* smat  = mymat ? bi : ai;
    const long  matoff = mymat ? 8192 : 0;
    const int   sq     = tid & 3;
    const int   wslot  = (((2 * sq) ^ (srow & 7)) << 4);

    // ---- lane-invariant swizzled read offsets (chunk c = 4ks+quad) ----
    int roff[4];
    {
        const int qh = quad >> 1, ql = quad & 1, c7 = col & 7;
#pragma unroll
        for (int ks = 0; ks < 4; ++ks)
            roff[ks] = col * 256 + ql * 128 + (((2 * ks + qh) ^ c7) << 4);
    }

    const int nh = 2 * (jt + 1);                    // halves; always >= 2, even
    float sum = 0.f;

    // prolog: half 0 -> buf0; issue half-1 loads
    StageF sEven = stagef_load(binp, smat, 0, srow, sq);
    stageh_write_cvt(ldsc, srow, matoff, wslot, sEven);
    StageF sOdd;
    if (nh > 1) sOdd = stagef_load(binp, smat, 1, srow, sq);

#pragma unroll 1
    for (int t = 0; t <= jt; ++t) {
        const int h2 = 2 * t + 2;

#pragma unroll
        for (int ph = 0; ph < 2; ++ph) {
            __syncthreads();        // prev compute on target buf done; cur buf published
            if (ph == 0) {
                stageh_write_cvt(ldsc + 16384, srow, matoff, wslot, sOdd);   // half 2t+1
                if (h2 < nh) sEven = stagef_load(binp, smat, h2, srow, sq);
            } else {
                if (h2 < nh)     stageh_write_cvt(ldsc, srow, matoff, wslot, sEven); // half 2t+2
                if (h2 + 1 < nh) sOdd = stagef_load(binp, smat, h2 + 1, srow, sq);
            }

            const char* buf     = ldsc + (ph ? 16384 : 0);
            const int   rowbase = t * 64 + ph * 32;

#pragma unroll
            for (int isub = 0; isub < 2; ++isub) {
                short8 av[4], bv[4];
#pragma unroll
                for (int ks = 0; ks < 4; ++ks) {
                    av[ks] = *(const short8*)(buf + isub * 4096 + roff[ks]);
                    bv[ks] = *(const short8*)(buf + 8192 + isub * 4096 + roff[ks]);
                }
                const int4 t4 = *(const int4*)(binp + 3 * SL + rowbase + isub * 16 + quad * 4);

                floatx4 aa = {0.f, 0.f, 0.f, 0.f};
                floatx4 bb = {1.f, 1.f, 1.f, 1.f};   // folds the "+1.0"
#pragma unroll
                for (int ks = 0; ks < 4; ++ks) {
                    aa = __builtin_amdgcn_mfma_f32_16x16x32_bf16(av[ks], bfa[ks], aa, 0, 0, 0);
                    bb = __builtin_amdgcn_mfma_f32_16x16x32_bf16(bv[ks], bfb[ks], bb, 0, 0, 0);
                }
#pragma unroll
                for (int rr = 0; rr < 4; ++rr) {
                    const int ti = (rr == 0) ? t4.x : (rr == 1) ? t4.y : (rr == 2) ? t4.z : t4.w;
                    const int dt = tj - ti;
                    // sorted times => (i<j && dt>0) <=> dt>0 ; dt==0 handled below
                    float lc  = __log2f((float)dt);               // junk if dt<=0, discarded
                    float nb  = fminf(fmaxf(bb[rr], 0.f), 10.f) * (-INV_LOG2_5);
                    float arg = (dt > 0) ? nb * lc : -__builtin_inff();
                    sum += aa[rr] * __builtin_amdgcn_exp2f(arg);
                }
            }
        }
    }

    // ---- reduce the 4 quads holding the same j ----
    sum += __shfl_xor(sum, 16, 64);
    sum += __shfl_xor(sum, 32, 64);

    // ---- fused finalize: dup-pair fp32 correction + biases + sigmoid ----
    if (quad == 0) {
        float corr = 0.f;
        for (int i = jlane - 1; i >= 0 && binp[3 * SL + i] == tj; --i) {
            const int ski = binp[i], li = binp[2 * SL + i];
            const long intr = ski + (long)li * NSK;
            corr += fixup_pair(ai + intr * EMB, bi + intr * EMB,
                               as + (long)sk_j * EMB, bs + (long)sk_j * EMB);
        }
        const float x = pbase[binp[SL + jlane]] + sbase[sk_j] + sum + corr;
        out[b * SL + jlane] = 1.f / (1.f + __expf(-x));
    }
}

extern "C" void kernel_launch(void* const* d_in, const int* in_sizes, int n_in,
                              void* d_out, int out_size, void* d_ws, size_t ws_size,
                              hipStream_t stream) {
    const int*   inp = (const int*)d_in[0];
    const float* pb  = (const float*)d_in[1];
    const float* sb  = (const float*)d_in[2];
    const float* ai  = (const float*)d_in[3];
    const float* as  = (const float*)d_in[4];
    const float* bi  = (const float*)d_in[5];
    const float* bs  = (const float*)d_in[6];

    hawkes_fused<<<dim3(16 * NB), dim3(256), 0, stream>>>(
        inp, pb, sb, ai, as, bi, bs, (float*)d_out);
}